// Round 7
// baseline (269.256 us; speedup 1.0000x reference)
//
#include <hip/hip_runtime.h>

typedef unsigned short u16;
typedef short bf16x8 __attribute__((ext_vector_type(8)));
typedef float f32x4 __attribute__((ext_vector_type(4)));

typedef __attribute__((address_space(3))) unsigned int lds_uint;
typedef __attribute__((address_space(1))) const unsigned int glob_uint;

__device__ __forceinline__ void gll16(const void* g, void* l) {
    __builtin_amdgcn_global_load_lds((glob_uint*)g, (lds_uint*)l, 16, 0, 0);
}

__device__ __forceinline__ u16 f2b(float f) {
    union { float f; unsigned int u; } cv; cv.f = f;
    unsigned int u = cv.u;
    u += 0x7fffu + ((u >> 16) & 1u);
    return (u16)(u >> 16);
}

__device__ __forceinline__ uint2 pack4(float a, float b, float c, float d) {
    uint2 r;
    r.x = (unsigned int)f2b(a) | ((unsigned int)f2b(b) << 16);
    r.y = (unsigned int)f2b(c) | ((unsigned int)f2b(d) << 16);
    return r;
}

// ---------------- prep: head-major weight reorder + bf16 convert ----------------
__global__ void prep_kernel(const float* __restrict__ wq, const float* __restrict__ wk,
                            const float* __restrict__ wv, const float* __restrict__ wo,
                            const float* __restrict__ bq, const float* __restrict__ bk,
                            const float* __restrict__ bv,
                            u16* __restrict__ wqkvh, u16* __restrict__ woT,
                            float* __restrict__ biash) {
    int idx = blockIdx.x * 256 + threadIdx.x;
    const int N1 = 512 * 1536;
    const int N2 = 512 * 512;
    if (idx < N1) {
        int k = idx / 1536, n2 = idx % 1536;
        int h = n2 / 192, j = n2 % 192;
        const float* w = (j < 64) ? wq : (j < 128) ? wk : wv;
        wqkvh[(size_t)n2 * 512 + k] = f2b(w[k * 512 + h * 64 + (j & 63)]);
    } else if (idx < N1 + N2) {
        int i = idx - N1;
        int k = i / 512, n = i % 512;
        woT[n * 512 + k] = f2b(wo[k * 512 + n]);
    } else if (idx < N1 + N2 + 1536) {
        int n2 = idx - N1 - N2;
        int h = n2 / 192, j = n2 % 192;
        const float* b = (j < 64) ? bq : (j < 128) ? bk : bv;
        biash[n2] = b[h * 64 + (j & 63)];
    }
}

// ---------------- pre: x fp32 -> bf16, window-shift permuted ----------------
__global__ __launch_bounds__(256) void pre_kernel(const float* __restrict__ x,
                                                  u16* __restrict__ xw) {
    int idx = blockIdx.x * 256 + threadIdx.x;      // 8 elems per thread
    int row = idx >> 6;
    int c = (idx & 63) * 8;
    int b_ = row >> 12, win = (row >> 6) & 63, t = row & 63;
    int wi = win >> 3, wj = win & 7, ti = t >> 3, tj = t & 7;
    int hh = (wi * 8 + ti + 4) & 63, ww = (wj * 8 + tj + 4) & 63;
    const float* src = x + ((size_t)b_ * 4096 + hh * 64 + ww) * 512 + c;
    float4 v0 = *(const float4*)src;
    float4 v1 = *(const float4*)(src + 4);
    ushort4 p0, p1;
    p0.x = f2b(v0.x); p0.y = f2b(v0.y); p0.z = f2b(v0.z); p0.w = f2b(v0.w);
    p1.x = f2b(v1.x); p1.y = f2b(v1.y); p1.z = f2b(v1.z); p1.w = f2b(v1.w);
    u16* dst = xw + (size_t)row * 512 + c;
    *(ushort4*)dst = p0;
    *(ushort4*)(dst + 4) = p1;
}

// ---------------- fused QKV + attention: one block per (window, head) ----------------
// (unchanged from R5 — structure is at its knee; see session notes)
__global__ __launch_bounds__(256, 4) void fused_qkv_attn(const u16* __restrict__ xw,
        const u16* __restrict__ wqkvh, const float* __restrict__ biash,
        u16* __restrict__ ows) {
    __shared__ u16 S[16384];
    const int tid = threadIdx.x;
    const int lane = tid & 63, wid = tid >> 6;
    const int wr = wid >> 1, wc = wid & 1;
    const int m = lane & 15, qd = lane >> 4;
    const int win = blockIdx.x & 511;
    const int h = blockIdx.x >> 9;
    const int rowBase = win * 64;

    u16* As  = S;
    u16* Bs  = S + 4096;
    u16* QKs = S;                    // aliases staging (dead at epilogue)
    u16* VT  = S + 8704;             // aliases Bs tail
    u16* Pw  = S + wid * 1152;       // aliases QKs (dead after QK^T barrier)

    const u16* Bsrc = wqkvh + (size_t)h * 192 * 512;
    f32x4 acc[2][6];
#pragma unroll
    for (int i = 0; i < 2; ++i)
#pragma unroll
        for (int j = 0; j < 6; ++j) acc[i][j] = (f32x4){0.f, 0.f, 0.f, 0.f};

    for (int kt = 0; kt < 8; ++kt) {
        const int k0 = kt * 64;
#pragma unroll
        for (int j = 0; j < 2; ++j) {
            int q = j * 256 + tid;
            int r = q >> 3, c = (q & 7) ^ (r & 7);
            gll16(xw + (size_t)(rowBase + r) * 512 + k0 + c * 8, As + q * 8);
        }
#pragma unroll
        for (int j = 0; j < 6; ++j) {
            int q = j * 256 + tid;
            int r = q >> 3, c = (q & 7) ^ (r & 7);
            gll16(Bsrc + (size_t)r * 512 + k0 + c * 8, Bs + q * 8);
        }
        __syncthreads();                 // staging visible
#pragma unroll
        for (int s = 0; s < 2; ++s) {
            bf16x8 a[2], b[6];
#pragma unroll
            for (int ni = 0; ni < 6; ++ni) {
                int R = wc * 96 + ni * 16 + m;
                b[ni] = *(const bf16x8*)&Bs[R * 64 + (((s * 4 + qd) ^ (R & 7)) * 8)];
            }
#pragma unroll
            for (int mi = 0; mi < 2; ++mi) {
                int R = wr * 32 + mi * 16 + m;
                a[mi] = *(const bf16x8*)&As[R * 64 + (((s * 4 + qd) ^ (R & 7)) * 8)];
            }
            // swapped: D[row=out-dim local qd*4+rr][col=token local m]
#pragma unroll
            for (int mi = 0; mi < 2; ++mi)
#pragma unroll
                for (int ni = 0; ni < 6; ++ni)
                    acc[mi][ni] = __builtin_amdgcn_mfma_f32_16x16x32_bf16(b[ni], a[mi], acc[mi][ni], 0, 0, 0);
        }
        __syncthreads();                 // all MFMA LDS reads done before restage/epilogue
    }

    // epilogue: Q,K -> QKs[t][0..127]; V -> VT[d][t]   (aliases dead staging)
#pragma unroll
    for (int mi = 0; mi < 2; ++mi) {
        int t = wr * 32 + mi * 16 + m;
#pragma unroll
        for (int ni = 0; ni < 6; ++ni) {
            int cn = wc * 96 + ni * 16;
            float4 bb = *(const float4*)&biash[h * 192 + cn + qd * 4];
            if (cn < 128) {
                *(uint2*)&QKs[t * 136 + cn + qd * 4] =
                    pack4(acc[mi][ni][0] + bb.x, acc[mi][ni][1] + bb.y,
                          acc[mi][ni][2] + bb.z, acc[mi][ni][3] + bb.w);
            } else {
                int d0 = cn - 128 + qd * 4;
                VT[(d0 + 0) * 72 + t] = f2b(acc[mi][ni][0] + bb.x);
                VT[(d0 + 1) * 72 + t] = f2b(acc[mi][ni][1] + bb.y);
                VT[(d0 + 2) * 72 + t] = f2b(acc[mi][ni][2] + bb.z);
                VT[(d0 + 3) * 72 + t] = f2b(acc[mi][ni][3] + bb.w);
            }
        }
    }
    __syncthreads();

    // ---- attention: wave handles S rows q0..q0+15 ----
    const int q0 = wid * 16;
    f32x4 sa[4];
#pragma unroll
    for (int ni = 0; ni < 4; ++ni) sa[ni] = (f32x4){0.f, 0.f, 0.f, 0.f};
#pragma unroll
    for (int s = 0; s < 2; ++s) {
        bf16x8 qf = *(const bf16x8*)&QKs[(q0 + m) * 136 + s * 32 + qd * 8];
#pragma unroll
        for (int ni = 0; ni < 4; ++ni) {
            bf16x8 kf = *(const bf16x8*)&QKs[(ni * 16 + m) * 136 + 64 + s * 32 + qd * 8];
            sa[ni] = __builtin_amdgcn_mfma_f32_16x16x32_bf16(qf, kf, sa[ni], 0, 0, 0);
        }
    }
    __syncthreads();   // QKs fully consumed -> P may alias it

    const float c1 = 0.125f * 1.4426950408889634f;
#pragma unroll
    for (int rr = 0; rr < 4; ++rr) {
        float mx = -3.4e38f;
#pragma unroll
        for (int ni = 0; ni < 4; ++ni) mx = fmaxf(mx, sa[ni][rr]);
        mx = fmaxf(mx, __shfl_xor(mx, 1, 64));
        mx = fmaxf(mx, __shfl_xor(mx, 2, 64));
        mx = fmaxf(mx, __shfl_xor(mx, 4, 64));
        mx = fmaxf(mx, __shfl_xor(mx, 8, 64));
        float sum = 0.f;
#pragma unroll
        for (int ni = 0; ni < 4; ++ni) {
            float p = exp2f((sa[ni][rr] - mx) * c1);
            sa[ni][rr] = p;
            sum += p;
        }
        sum += __shfl_xor(sum, 1, 64);
        sum += __shfl_xor(sum, 2, 64);
        sum += __shfl_xor(sum, 4, 64);
        sum += __shfl_xor(sum, 8, 64);
        float inv = 1.f / sum;
        int r = qd * 4 + rr;
#pragma unroll
        for (int ni = 0; ni < 4; ++ni)
            Pw[r * 72 + ni * 16 + m] = f2b(sa[ni][rr] * inv);
    }

    f32x4 oa[4];
#pragma unroll
    for (int ni = 0; ni < 4; ++ni) oa[ni] = (f32x4){0.f, 0.f, 0.f, 0.f};
#pragma unroll
    for (int s = 0; s < 2; ++s) {
        bf16x8 pf = *(const bf16x8*)&Pw[m * 72 + s * 32 + qd * 8];
#pragma unroll
        for (int ni = 0; ni < 4; ++ni) {
            bf16x8 vf = *(const bf16x8*)&VT[(ni * 16 + m) * 72 + s * 32 + qd * 8];
            // swapped: D[row=d local][col=q-token local]
            oa[ni] = __builtin_amdgcn_mfma_f32_16x16x32_bf16(vf, pf, oa[ni], 0, 0, 0);
        }
    }
    u16* dst = ows + (size_t)(rowBase + q0 + m) * 512 + h * 64;
#pragma unroll
    for (int ni = 0; ni < 4; ++ni)
        *(uint2*)&dst[ni * 16 + qd * 4] =
            pack4(oa[ni][0], oa[ni][1], oa[ni][2], oa[ni][3]);
}

// ---------------- proj GEMM: M=32768 N=512 K=512, BK=64 ----------------
// XCD-chunked block swizzle (T1): dispatch order is x-fastest, so the 4 col-tile
// blocks sharing the same 128 A-rows were landing on 4 DIFFERENT XCDs -> A panel
// fetched 4x from HBM (~128 MB). swz groups 128 consecutive flat-ids per XCD =
// 32 row-tiles x all 4 col-tiles -> A-sharing blocks co-located on one XCD's L2.
// 1024 % 8 == 0 -> simple swizzle is bijective.
__global__ __launch_bounds__(256) void proj_gemm(const u16* __restrict__ ows,
        const u16* __restrict__ woT, const float* __restrict__ bo,
        const float* __restrict__ x, float* __restrict__ out) {
    __shared__ u16 S[16384];           // As@0, Bs@8192 (u16); epilogue: Ct fp32 alias
    u16* As = S;
    u16* Bs = S + 8192;
    const int tid = threadIdx.x;
    const int lane = tid & 63, wid = tid >> 6;
    const int wr = wid >> 1, wc = wid & 1;
    const int m = lane & 15, qd = lane >> 4;
    const int flat = blockIdx.y * 4 + blockIdx.x;
    const int swz = (flat & 7) * 128 + (flat >> 3);
    const int rowBase = (swz >> 2) * 128;
    const int colBase = (swz & 3) * 128;
    const int c8 = (lane & 7) ^ (lane >> 3);

    f32x4 acc[4][4];
#pragma unroll
    for (int i = 0; i < 4; ++i)
#pragma unroll
        for (int j = 0; j < 4; ++j) acc[i][j] = (f32x4){0.f, 0.f, 0.f, 0.f};

    for (int kt = 0; kt < 8; ++kt) {
        const int k0 = kt * 64;
        __syncthreads();
#pragma unroll
        for (int j = 0; j < 4; ++j) {
            int q = (j * 4 + wid) * 64 + lane;
            int r = (j * 4 + wid) * 8 + (lane >> 3);
            gll16(ows + (size_t)(rowBase + r) * 512 + k0 + c8 * 8, &As[q * 8]);
            gll16(woT + (size_t)(colBase + r) * 512 + k0 + c8 * 8, &Bs[q * 8]);
        }
        __syncthreads();
#pragma unroll
        for (int s = 0; s < 2; ++s) {
            bf16x8 a[4], b[4];
#pragma unroll
            for (int ni = 0; ni < 4; ++ni) {
                int R = wc * 64 + ni * 16 + m;
                b[ni] = *(const bf16x8*)&Bs[R * 64 + (((s * 4 + qd) ^ (R & 7)) * 8)];
            }
#pragma unroll
            for (int mi = 0; mi < 4; ++mi) {
                int R = wr * 64 + mi * 16 + m;
                a[mi] = *(const bf16x8*)&As[R * 64 + (((s * 4 + qd) ^ (R & 7)) * 8)];
            }
            // swapped: D[row=col-dim local][col=token local]
#pragma unroll
            for (int mi = 0; mi < 4; ++mi)
#pragma unroll
                for (int ni = 0; ni < 4; ++ni)
                    acc[mi][ni] = __builtin_amdgcn_mfma_f32_16x16x32_bf16(b[ni], a[mi], acc[mi][ni], 0, 0, 0);
        }
    }
    __syncthreads();                   // staging dead -> Ct may alias

    float* Ct = (float*)S;             // [64 tok][128 col], chunk-XOR swizzled
    for (int p = 0; p < 2; ++p) {
        if (wr == p) {
#pragma unroll
            for (int mi = 0; mi < 4; ++mi) {
                int r = mi * 16 + m;   // token-local within this pass
#pragma unroll
                for (int ni = 0; ni < 4; ++ni) {
                    int ch = (wc * 16 + ni * 4 + qd) ^ (r & 7);
                    *(f32x4*)&Ct[r * 128 + ch * 4] = acc[mi][ni];
                }
            }
        }
        __syncthreads();
        {
            int k = tid >> 2, cseg = tid & 3;      // token-local, 32-col segment
            int row = rowBase + p * 64 + k;        // win*64 + t
            int win = row >> 6, t = row & 63;
            int b_ = win >> 6, wh = (win >> 3) & 7, ww_ = win & 7;
            int ti = t >> 3, tj = t & 7;
            int hh = (wh * 8 + ti + 4) & 63;
            int www = (ww_ * 8 + tj + 4) & 63;
            size_t tok = (size_t)b_ * 4096 + hh * 64 + www;
            const float* xs = &x[tok * 512 + colBase + cseg * 32];
            const float* bs = &bo[colBase + cseg * 32];
            float* os = &out[tok * 512 + colBase + cseg * 32];
#pragma unroll
            for (int j = 0; j < 8; ++j) {
                int ch = (cseg * 8 + j) ^ (k & 7);
                f32x4 c = *(const f32x4*)&Ct[k * 128 + ch * 4];
                float4 xv = *(const float4*)&xs[j * 4];
                float4 bv = *(const float4*)&bs[j * 4];
                float4 o;
                o.x = c[0] + bv.x + xv.x;
                o.y = c[1] + bv.y + xv.y;
                o.z = c[2] + bv.z + xv.z;
                o.w = c[3] + bv.w + xv.w;
                *(float4*)&os[j * 4] = o;
            }
        }
        __syncthreads();
    }
}

extern "C" void kernel_launch(void* const* d_in, const int* in_sizes, int n_in,
                              void* d_out, int out_size, void* d_ws, size_t ws_size,
                              hipStream_t stream) {
    const float* x  = (const float*)d_in[0];
    const float* wq = (const float*)d_in[1];
    const float* bq = (const float*)d_in[2];
    const float* wk = (const float*)d_in[3];
    const float* bk = (const float*)d_in[4];
    const float* wv = (const float*)d_in[5];
    const float* bv = (const float*)d_in[6];
    const float* wo = (const float*)d_in[7];
    const float* bo = (const float*)d_in[8];
    float* out = (float*)d_out;
    char* ws = (char*)d_ws;

    u16*   wqkvh = (u16*)ws;                               // 1536*512*2
    u16*   woT   = (u16*)(ws + 1572864);                   // 512*512*2
    float* biash = (float*)(ws + 1572864 + 524288);        // 1536*4
    size_t off = 2103296;
    u16* xw  = (u16*)(ws + off);                           // 32768*512 u16 = 32 MiB
    u16* ows = xw + (size_t)16777216;                      // 32768*512 u16 = 32 MiB

    const int prepN = 512 * 1536 + 512 * 512 + 1536;
    prep_kernel<<<dim3((prepN + 255) / 256), dim3(256), 0, stream>>>(
        wq, wk, wv, wo, bq, bk, bv, wqkvh, woT, biash);
    pre_kernel<<<dim3(8192), dim3(256), 0, stream>>>(x, xw);
    fused_qkv_attn<<<dim3(4096), dim3(256), 0, stream>>>(xw, wqkvh, biash, ows);
    proj_gemm<<<dim3(4, 256), dim3(256), 0, stream>>>(ows, woT, bo, x, out);
}

// Round 8
// 266.074 us; speedup vs baseline: 1.0120x; 1.0120x over previous
//
#include <hip/hip_runtime.h>

typedef unsigned short u16;
typedef short bf16x8 __attribute__((ext_vector_type(8)));
typedef float f32x4 __attribute__((ext_vector_type(4)));

typedef __attribute__((address_space(3))) unsigned int lds_uint;
typedef __attribute__((address_space(1))) const unsigned int glob_uint;

__device__ __forceinline__ void gll16(const void* g, void* l) {
    __builtin_amdgcn_global_load_lds((glob_uint*)g, (lds_uint*)l, 16, 0, 0);
}

__device__ __forceinline__ u16 f2b(float f) {
    union { float f; unsigned int u; } cv; cv.f = f;
    unsigned int u = cv.u;
    u += 0x7fffu + ((u >> 16) & 1u);
    return (u16)(u >> 16);
}

__device__ __forceinline__ uint2 pack4(float a, float b, float c, float d) {
    uint2 r;
    r.x = (unsigned int)f2b(a) | ((unsigned int)f2b(b) << 16);
    r.y = (unsigned int)f2b(c) | ((unsigned int)f2b(d) << 16);
    return r;
}

// ---------------- prep: head-major weight reorder + bf16 convert ----------------
__global__ void prep_kernel(const float* __restrict__ wq, const float* __restrict__ wk,
                            const float* __restrict__ wv, const float* __restrict__ wo,
                            const float* __restrict__ bq, const float* __restrict__ bk,
                            const float* __restrict__ bv,
                            u16* __restrict__ wqkvh, u16* __restrict__ woT,
                            float* __restrict__ biash) {
    int idx = blockIdx.x * 256 + threadIdx.x;
    const int N1 = 512 * 1536;
    const int N2 = 512 * 512;
    if (idx < N1) {
        int k = idx / 1536, n2 = idx % 1536;
        int h = n2 / 192, j = n2 % 192;
        const float* w = (j < 64) ? wq : (j < 128) ? wk : wv;
        wqkvh[(size_t)n2 * 512 + k] = f2b(w[k * 512 + h * 64 + (j & 63)]);
    } else if (idx < N1 + N2) {
        int i = idx - N1;
        int k = i / 512, n = i % 512;
        woT[n * 512 + k] = f2b(wo[k * 512 + n]);
    } else if (idx < N1 + N2 + 1536) {
        int n2 = idx - N1 - N2;
        int h = n2 / 192, j = n2 % 192;
        const float* b = (j < 64) ? bq : (j < 128) ? bk : bv;
        biash[n2] = b[h * 64 + (j & 63)];
    }
}

// ---------------- pre: x fp32 -> bf16, window-shift permuted ----------------
__global__ __launch_bounds__(256) void pre_kernel(const float* __restrict__ x,
                                                  u16* __restrict__ xw) {
    int idx = blockIdx.x * 256 + threadIdx.x;      // 8 elems per thread
    int row = idx >> 6;
    int c = (idx & 63) * 8;
    int b_ = row >> 12, win = (row >> 6) & 63, t = row & 63;
    int wi = win >> 3, wj = win & 7, ti = t >> 3, tj = t & 7;
    int hh = (wi * 8 + ti + 4) & 63, ww = (wj * 8 + tj + 4) & 63;
    const float* src = x + ((size_t)b_ * 4096 + hh * 64 + ww) * 512 + c;
    float4 v0 = *(const float4*)src;
    float4 v1 = *(const float4*)(src + 4);
    ushort4 p0, p1;
    p0.x = f2b(v0.x); p0.y = f2b(v0.y); p0.z = f2b(v0.z); p0.w = f2b(v0.w);
    p1.x = f2b(v1.x); p1.y = f2b(v1.y); p1.z = f2b(v1.z); p1.w = f2b(v1.w);
    u16* dst = xw + (size_t)row * 512 + c;
    *(ushort4*)dst = p0;
    *(ushort4*)(dst + 4) = p1;
}

// ---------------- fused QKV + attention: one block per (window, head) ----------------
// R8: T3/T4 minimum 2-phase pipeline. BK=32, double-buffered staging (2x16KB = 32KB
// total, 5 blocks/CU kept). Per K-step: issue next tile's 4 gll16, s_waitcnt vmcnt(4)
// (counted — next tile's loads stay in flight), raw s_barrier, ds_read+12 MFMA,
// lgkmcnt(0)+sched_barrier+s_barrier. Stage latency hides under compute.
// LDS (u16): A0[0,2048) B0[2048,8192) A1[8192,10240) B1[10240,16384)
//   attention aliases (after final full barrier): QKs@0 (64x136) VT@8704 (64x72)
//   Pw@wid*1152 (after QK^T barrier, over dead QKs).
// Read swizzle for 32-u16 rows: chunk = qd ^ ((R>>1)&3) -> 2-way bank alias (free).
// Staging pre-swizzles the GLOBAL source col so LDS dest stays linear (m173).
__global__ __launch_bounds__(256, 4) void fused_qkv_attn(const u16* __restrict__ xw,
        const u16* __restrict__ wqkvh, const float* __restrict__ biash,
        u16* __restrict__ ows) {
    __shared__ u16 S[16384];
    const int tid = threadIdx.x;
    const int lane = tid & 63, wid = tid >> 6;
    const int wr = wid >> 1, wc = wid & 1;
    const int m = lane & 15, qd = lane >> 4;
    const int win = blockIdx.x & 511;
    const int h = blockIdx.x >> 9;
    const int rowBase = win * 64;

    u16* const A0 = S;
    u16* const B0 = S + 2048;
    u16* const A1 = S + 8192;
    u16* const B1 = S + 10240;
    u16* QKs = S;                    // aliases staging (dead at epilogue)
    u16* VT  = S + 8704;             // aliases A1/B1
    u16* Pw  = S + wid * 1152;       // aliases QKs (dead after QK^T barrier)

    const u16* xwRow = xw + (size_t)rowBase * 512;
    const u16* Bsrc  = wqkvh + (size_t)h * 192 * 512;

    // per-thread staging source precompute (dst stays linear: q*8 u16)
    const int rA = tid >> 2;
    const int cA = (tid & 3) ^ ((rA >> 1) & 3);

    f32x4 acc[2][6];
#pragma unroll
    for (int i = 0; i < 2; ++i)
#pragma unroll
        for (int j = 0; j < 6; ++j) acc[i][j] = (f32x4){0.f, 0.f, 0.f, 0.f};

#define STAGE(K0, DA, DB)                                                    \
    {                                                                        \
        gll16(xwRow + (size_t)rA * 512 + (K0) + cA * 8, (DA) + tid * 8);     \
        _Pragma("unroll")                                                    \
        for (int j = 0; j < 3; ++j) {                                        \
            int q = j * 256 + tid;                                           \
            int r = q >> 2;                                                  \
            int cl = (q & 3) ^ ((r >> 1) & 3);                               \
            gll16(Bsrc + (size_t)r * 512 + (K0) + cl * 8, (DB) + q * 8);     \
        }                                                                    \
    }

#define COMPUTE(SA, SB)                                                      \
    {                                                                        \
        bf16x8 a[2], b[6];                                                   \
        _Pragma("unroll")                                                    \
        for (int ni = 0; ni < 6; ++ni) {                                     \
            int R = wc * 96 + ni * 16 + m;                                   \
            b[ni] = *(const bf16x8*)&(SB)[R * 32 + ((qd ^ ((R >> 1) & 3)) * 8)]; \
        }                                                                    \
        _Pragma("unroll")                                                    \
        for (int mi = 0; mi < 2; ++mi) {                                     \
            int R = wr * 32 + mi * 16 + m;                                   \
            a[mi] = *(const bf16x8*)&(SA)[R * 32 + ((qd ^ ((R >> 1) & 3)) * 8)]; \
        }                                                                    \
        _Pragma("unroll")                                                    \
        for (int mi = 0; mi < 2; ++mi)                                       \
            _Pragma("unroll")                                                \
            for (int ni = 0; ni < 6; ++ni)                                   \
                acc[mi][ni] = __builtin_amdgcn_mfma_f32_16x16x32_bf16(       \
                    b[ni], a[mi], acc[mi][ni], 0, 0, 0);                     \
    }

    // prologue: stage tile 0 into buf0
    STAGE(0, A0, B0);
    {
        u16 *curA = A0, *curB = B0, *nxtA = A1, *nxtB = B1;
#pragma unroll 1
        for (int kt = 0; kt < 15; ++kt) {
            STAGE((kt + 1) * 32, nxtA, nxtB);
            asm volatile("s_waitcnt vmcnt(4)" ::: "memory");   // cur tile landed
            __builtin_amdgcn_s_barrier();
            __builtin_amdgcn_sched_barrier(0);
            COMPUTE(curA, curB);
            asm volatile("s_waitcnt lgkmcnt(0)" ::: "memory"); // LDS reads done
            __builtin_amdgcn_sched_barrier(0);
            __builtin_amdgcn_s_barrier();                      // buf reusable
            u16* t;
            t = curA; curA = nxtA; nxtA = t;
            t = curB; curB = nxtB; nxtB = t;
        }
        // tail: tile 15 (staged in kt=14)
        asm volatile("s_waitcnt vmcnt(0)" ::: "memory");
        __builtin_amdgcn_s_barrier();
        __builtin_amdgcn_sched_barrier(0);
        COMPUTE(curA, curB);
    }
#undef STAGE
#undef COMPUTE
    __syncthreads();                 // full drain; staging dead -> epilogue aliases

    // epilogue: Q,K -> QKs[t][0..127]; V -> VT[d][t]
#pragma unroll
    for (int mi = 0; mi < 2; ++mi) {
        int t = wr * 32 + mi * 16 + m;
#pragma unroll
        for (int ni = 0; ni < 6; ++ni) {
            int cn = wc * 96 + ni * 16;
            float4 bb = *(const float4*)&biash[h * 192 + cn + qd * 4];
            if (cn < 128) {
                *(uint2*)&QKs[t * 136 + cn + qd * 4] =
                    pack4(acc[mi][ni][0] + bb.x, acc[mi][ni][1] + bb.y,
                          acc[mi][ni][2] + bb.z, acc[mi][ni][3] + bb.w);
            } else {
                int d0 = cn - 128 + qd * 4;
                VT[(d0 + 0) * 72 + t] = f2b(acc[mi][ni][0] + bb.x);
                VT[(d0 + 1) * 72 + t] = f2b(acc[mi][ni][1] + bb.y);
                VT[(d0 + 2) * 72 + t] = f2b(acc[mi][ni][2] + bb.z);
                VT[(d0 + 3) * 72 + t] = f2b(acc[mi][ni][3] + bb.w);
            }
        }
    }
    __syncthreads();

    // ---- attention: wave handles S rows q0..q0+15 ----
    const int q0 = wid * 16;
    f32x4 sa[4];
#pragma unroll
    for (int ni = 0; ni < 4; ++ni) sa[ni] = (f32x4){0.f, 0.f, 0.f, 0.f};
#pragma unroll
    for (int s = 0; s < 2; ++s) {
        bf16x8 qf = *(const bf16x8*)&QKs[(q0 + m) * 136 + s * 32 + qd * 8];
#pragma unroll
        for (int ni = 0; ni < 4; ++ni) {
            bf16x8 kf = *(const bf16x8*)&QKs[(ni * 16 + m) * 136 + 64 + s * 32 + qd * 8];
            sa[ni] = __builtin_amdgcn_mfma_f32_16x16x32_bf16(qf, kf, sa[ni], 0, 0, 0);
        }
    }
    __syncthreads();   // QKs fully consumed -> P may alias it

    const float c1 = 0.125f * 1.4426950408889634f;
#pragma unroll
    for (int rr = 0; rr < 4; ++rr) {
        float mx = -3.4e38f;
#pragma unroll
        for (int ni = 0; ni < 4; ++ni) mx = fmaxf(mx, sa[ni][rr]);
        mx = fmaxf(mx, __shfl_xor(mx, 1, 64));
        mx = fmaxf(mx, __shfl_xor(mx, 2, 64));
        mx = fmaxf(mx, __shfl_xor(mx, 4, 64));
        mx = fmaxf(mx, __shfl_xor(mx, 8, 64));
        float sum = 0.f;
#pragma unroll
        for (int ni = 0; ni < 4; ++ni) {
            float p = exp2f((sa[ni][rr] - mx) * c1);
            sa[ni][rr] = p;
            sum += p;
        }
        sum += __shfl_xor(sum, 1, 64);
        sum += __shfl_xor(sum, 2, 64);
        sum += __shfl_xor(sum, 4, 64);
        sum += __shfl_xor(sum, 8, 64);
        float inv = 1.f / sum;
        int r = qd * 4 + rr;
#pragma unroll
        for (int ni = 0; ni < 4; ++ni)
            Pw[r * 72 + ni * 16 + m] = f2b(sa[ni][rr] * inv);
    }

    f32x4 oa[4];
#pragma unroll
    for (int ni = 0; ni < 4; ++ni) oa[ni] = (f32x4){0.f, 0.f, 0.f, 0.f};
#pragma unroll
    for (int s = 0; s < 2; ++s) {
        bf16x8 pf = *(const bf16x8*)&Pw[m * 72 + s * 32 + qd * 8];
#pragma unroll
        for (int ni = 0; ni < 4; ++ni) {
            bf16x8 vf = *(const bf16x8*)&VT[(ni * 16 + m) * 72 + s * 32 + qd * 8];
            // swapped: D[row=d local][col=q-token local]
            oa[ni] = __builtin_amdgcn_mfma_f32_16x16x32_bf16(vf, pf, oa[ni], 0, 0, 0);
        }
    }
    u16* dst = ows + (size_t)(rowBase + q0 + m) * 512 + h * 64;
#pragma unroll
    for (int ni = 0; ni < 4; ++ni)
        *(uint2*)&dst[ni * 16 + qd * 4] =
            pack4(oa[ni][0], oa[ni][1], oa[ni][2], oa[ni][3]);
}

// ---------------- proj GEMM: M=32768 N=512 K=512, BK=64 (R6 version, swizzle reverted) ----
__global__ __launch_bounds__(256) void proj_gemm(const u16* __restrict__ ows,
        const u16* __restrict__ woT, const float* __restrict__ bo,
        const float* __restrict__ x, float* __restrict__ out) {
    __shared__ u16 S[16384];           // As@0, Bs@8192 (u16); epilogue: Ct fp32 alias
    u16* As = S;
    u16* Bs = S + 8192;
    const int tid = threadIdx.x;
    const int lane = tid & 63, wid = tid >> 6;
    const int wr = wid >> 1, wc = wid & 1;
    const int m = lane & 15, qd = lane >> 4;
    const int rowBase = blockIdx.y * 128;
    const int colBase = blockIdx.x * 128;
    const int c8 = (lane & 7) ^ (lane >> 3);

    f32x4 acc[4][4];
#pragma unroll
    for (int i = 0; i < 4; ++i)
#pragma unroll
        for (int j = 0; j < 4; ++j) acc[i][j] = (f32x4){0.f, 0.f, 0.f, 0.f};

    for (int kt = 0; kt < 8; ++kt) {
        const int k0 = kt * 64;
        __syncthreads();
#pragma unroll
        for (int j = 0; j < 4; ++j) {
            int q = (j * 4 + wid) * 64 + lane;
            int r = (j * 4 + wid) * 8 + (lane >> 3);
            gll16(ows + (size_t)(rowBase + r) * 512 + k0 + c8 * 8, &As[q * 8]);
            gll16(woT + (size_t)(colBase + r) * 512 + k0 + c8 * 8, &Bs[q * 8]);
        }
        __syncthreads();
#pragma unroll
        for (int s = 0; s < 2; ++s) {
            bf16x8 a[4], b[4];
#pragma unroll
            for (int ni = 0; ni < 4; ++ni) {
                int R = wc * 64 + ni * 16 + m;
                b[ni] = *(const bf16x8*)&Bs[R * 64 + (((s * 4 + qd) ^ (R & 7)) * 8)];
            }
#pragma unroll
            for (int mi = 0; mi < 4; ++mi) {
                int R = wr * 64 + mi * 16 + m;
                a[mi] = *(const bf16x8*)&As[R * 64 + (((s * 4 + qd) ^ (R & 7)) * 8)];
            }
            // swapped: D[row=col-dim local][col=token local]
#pragma unroll
            for (int mi = 0; mi < 4; ++mi)
#pragma unroll
                for (int ni = 0; ni < 4; ++ni)
                    acc[mi][ni] = __builtin_amdgcn_mfma_f32_16x16x32_bf16(b[ni], a[mi], acc[mi][ni], 0, 0, 0);
        }
    }
    __syncthreads();                   // staging dead -> Ct may alias

    float* Ct = (float*)S;             // [64 tok][128 col], chunk-XOR swizzled
    for (int p = 0; p < 2; ++p) {
        if (wr == p) {
#pragma unroll
            for (int mi = 0; mi < 4; ++mi) {
                int r = mi * 16 + m;   // token-local within this pass
#pragma unroll
                for (int ni = 0; ni < 4; ++ni) {
                    int ch = (wc * 16 + ni * 4 + qd) ^ (r & 7);
                    *(f32x4*)&Ct[r * 128 + ch * 4] = acc[mi][ni];
                }
            }
        }
        __syncthreads();
        {
            int k = tid >> 2, cseg = tid & 3;      // token-local, 32-col segment
            int row = rowBase + p * 64 + k;        // win*64 + t
            int win = row >> 6, t = row & 63;
            int b_ = win >> 6, wh = (win >> 3) & 7, ww_ = win & 7;
            int ti = t >> 3, tj = t & 7;
            int hh = (wh * 8 + ti + 4) & 63;
            int www = (ww_ * 8 + tj + 4) & 63;
            size_t tok = (size_t)b_ * 4096 + hh * 64 + www;
            const float* xs = &x[tok * 512 + colBase + cseg * 32];
            const float* bs = &bo[colBase + cseg * 32];
            float* os = &out[tok * 512 + colBase + cseg * 32];
#pragma unroll
            for (int j = 0; j < 8; ++j) {
                int ch = (cseg * 8 + j) ^ (k & 7);
                f32x4 c = *(const f32x4*)&Ct[k * 128 + ch * 4];
                float4 xv = *(const float4*)&xs[j * 4];
                float4 bv = *(const float4*)&bs[j * 4];
                float4 o;
                o.x = c[0] + bv.x + xv.x;
                o.y = c[1] + bv.y + xv.y;
                o.z = c[2] + bv.z + xv.z;
                o.w = c[3] + bv.w + xv.w;
                *(float4*)&os[j * 4] = o;
            }
        }
        __syncthreads();
    }
}

extern "C" void kernel_launch(void* const* d_in, const int* in_sizes, int n_in,
                              void* d_out, int out_size, void* d_ws, size_t ws_size,
                              hipStream_t stream) {
    const float* x  = (const float*)d_in[0];
    const float* wq = (const float*)d_in[1];
    const float* bq = (const float*)d_in[2];
    const float* wk = (const float*)d_in[3];
    const float* bk = (const float*)d_in[4];
    const float* wv = (const float*)d_in[5];
    const float* bv = (const float*)d_in[6];
    const float* wo = (const float*)d_in[7];
    const float* bo = (const float*)d_in[8];
    float* out = (float*)d_out;
    char* ws = (char*)d_ws;

    u16*   wqkvh = (u16*)ws;                               // 1536*512*2
    u16*   woT   = (u16*)(ws + 1572864);                   // 512*512*2
    float* biash = (float*)(ws + 1572864 + 524288);        // 1536*4
    size_t off = 2103296;
    u16* xw  = (u16*)(ws + off);                           // 32768*512 u16 = 32 MiB
    u16* ows = xw + (size_t)16777216;                      // 32768*512 u16 = 32 MiB

    const int prepN = 512 * 1536 + 512 * 512 + 1536;
    prep_kernel<<<dim3((prepN + 255) / 256), dim3(256), 0, stream>>>(
        wq, wk, wv, wo, bq, bk, bv, wqkvh, woT, biash);
    pre_kernel<<<dim3(8192), dim3(256), 0, stream>>>(x, xw);
    fused_qkv_attn<<<dim3(4096), dim3(256), 0, stream>>>(xw, wqkvh, biash, ows);
    proj_gemm<<<dim3(4, 256), dim3(256), 0, stream>>>(ows, woT, bo, x, out);
}

// Round 9
// 258.364 us; speedup vs baseline: 1.0422x; 1.0298x over previous
//
#include <hip/hip_runtime.h>

typedef unsigned short u16;
typedef short bf16x8 __attribute__((ext_vector_type(8)));
typedef float f32x4 __attribute__((ext_vector_type(4)));

typedef __attribute__((address_space(3))) unsigned int lds_uint;
typedef __attribute__((address_space(1))) const unsigned int glob_uint;

__device__ __forceinline__ void gll16(const void* g, void* l) {
    __builtin_amdgcn_global_load_lds((glob_uint*)g, (lds_uint*)l, 16, 0, 0);
}

__device__ __forceinline__ u16 f2b(float f) {
    union { float f; unsigned int u; } cv; cv.f = f;
    unsigned int u = cv.u;
    u += 0x7fffu + ((u >> 16) & 1u);
    return (u16)(u >> 16);
}

__device__ __forceinline__ uint2 pack4(float a, float b, float c, float d) {
    uint2 r;
    r.x = (unsigned int)f2b(a) | ((unsigned int)f2b(b) << 16);
    r.y = (unsigned int)f2b(c) | ((unsigned int)f2b(d) << 16);
    return r;
}

// ---------------- prep: head-major weight reorder + bf16 convert ----------------
__global__ void prep_kernel(const float* __restrict__ wq, const float* __restrict__ wk,
                            const float* __restrict__ wv, const float* __restrict__ wo,
                            const float* __restrict__ bq, const float* __restrict__ bk,
                            const float* __restrict__ bv,
                            u16* __restrict__ wqkvh, u16* __restrict__ woT,
                            float* __restrict__ biash) {
    int idx = blockIdx.x * 256 + threadIdx.x;
    const int N1 = 512 * 1536;
    const int N2 = 512 * 512;
    if (idx < N1) {
        int k = idx / 1536, n2 = idx % 1536;
        int h = n2 / 192, j = n2 % 192;
        const float* w = (j < 64) ? wq : (j < 128) ? wk : wv;
        wqkvh[(size_t)n2 * 512 + k] = f2b(w[k * 512 + h * 64 + (j & 63)]);
    } else if (idx < N1 + N2) {
        int i = idx - N1;
        int k = i / 512, n = i % 512;
        woT[n * 512 + k] = f2b(wo[k * 512 + n]);
    } else if (idx < N1 + N2 + 1536) {
        int n2 = idx - N1 - N2;
        int h = n2 / 192, j = n2 % 192;
        const float* b = (j < 64) ? bq : (j < 128) ? bk : bv;
        biash[n2] = b[h * 64 + (j & 63)];
    }
}

// ---------------- pre: x fp32 -> bf16, window-shift permuted ----------------
__global__ __launch_bounds__(256) void pre_kernel(const float* __restrict__ x,
                                                  u16* __restrict__ xw) {
    int idx = blockIdx.x * 256 + threadIdx.x;      // 8 elems per thread
    int row = idx >> 6;
    int c = (idx & 63) * 8;
    int b_ = row >> 12, win = (row >> 6) & 63, t = row & 63;
    int wi = win >> 3, wj = win & 7, ti = t >> 3, tj = t & 7;
    int hh = (wi * 8 + ti + 4) & 63, ww = (wj * 8 + tj + 4) & 63;
    const float* src = x + ((size_t)b_ * 4096 + hh * 64 + ww) * 512 + c;
    float4 v0 = *(const float4*)src;
    float4 v1 = *(const float4*)(src + 4);
    ushort4 p0, p1;
    p0.x = f2b(v0.x); p0.y = f2b(v0.y); p0.z = f2b(v0.z); p0.w = f2b(v0.w);
    p1.x = f2b(v1.x); p1.y = f2b(v1.y); p1.z = f2b(v1.z); p1.w = f2b(v1.w);
    u16* dst = xw + (size_t)row * 512 + c;
    *(ushort4*)dst = p0;
    *(ushort4*)(dst + 4) = p1;
}

// ---------------- fused QKV + attention: one block per (window-PAIR, head) ----------------
// R9: M=128 (two windows), 512 threads / 8 waves, BK=64, 2-barrier loop (R5's proven
// sync structure). B slab staged once per PAIR -> total staged bytes 1GB -> 640MB.
// Wave tiling: wr = wid>>1 (M, 32 rows each), wc = wid&1 (N, 96 cols). acc[2][6]
// per wave (same reg shape as R5's 64-VGPR kernel).
// Grid 2048: wp = bid & 255, h = bid >> 8 (stride-256, 256%8==0 -> pair's heads on 1 XCD).
// LDS (u16): As[0,8192) 128x64; Bs[8192,20480) 192x64.  After GEMM, per-window
// aliases: QKs@0 (64x136=8704), VT@8704 (64x72=4608), Pw@13312+slot*1152 (no alias
// with QKs -> no mid-attention barrier). Total 40960 B.
// Window w is produced by waves wid>>2==w (rows [w*64,(w+1)*64)) and its attention
// runs on the same 4 waves (slot = wid&3) -> sequential windows, 2 barriers each.
__global__ __launch_bounds__(512) void fused_qkv_attn(const u16* __restrict__ xw,
        const u16* __restrict__ wqkvh, const float* __restrict__ biash,
        u16* __restrict__ ows) {
    __shared__ u16 S[20480];
    const int tid = threadIdx.x;
    const int lane = tid & 63, wid = tid >> 6;
    const int wr = wid >> 1, wc = wid & 1;      // wr 0..3 (M), wc 0..1 (N)
    const int g = wid >> 2;                     // window group 0/1
    const int slot = wid & 3;                   // attention wave slot
    const int m = lane & 15, qd = lane >> 4;
    const int wp = blockIdx.x & 255;
    const int h = blockIdx.x >> 8;
    const int rowBase = wp * 128;

    u16* As  = S;                     // [128][64]
    u16* Bs  = S + 8192;              // [192][64]
    u16* QKs = S;                     // aliases staging (dead at epilogue)
    u16* VT  = S + 8704;              // aliases Bs
    u16* Pw  = S + 13312 + slot * 1152;   // separate region, no QKs alias

    const u16* Bsrc = wqkvh + (size_t)h * 192 * 512;
    f32x4 acc[2][6];
#pragma unroll
    for (int i = 0; i < 2; ++i)
#pragma unroll
        for (int j = 0; j < 6; ++j) acc[i][j] = (f32x4){0.f, 0.f, 0.f, 0.f};

    for (int kt = 0; kt < 8; ++kt) {
        const int k0 = kt * 64;
#pragma unroll
        for (int j = 0; j < 2; ++j) {          // A: 128x64 = 1024 loads / 512 thr
            int q = j * 512 + tid;
            int r = q >> 3, c = (q & 7) ^ (r & 7);
            gll16(xw + (size_t)(rowBase + r) * 512 + k0 + c * 8, As + q * 8);
        }
#pragma unroll
        for (int j = 0; j < 3; ++j) {          // B: 192x64 = 1536 loads / 512 thr
            int q = j * 512 + tid;
            int r = q >> 3, c = (q & 7) ^ (r & 7);
            gll16(Bsrc + (size_t)r * 512 + k0 + c * 8, Bs + q * 8);
        }
        __syncthreads();                 // staging visible
#pragma unroll
        for (int s = 0; s < 2; ++s) {
            bf16x8 a[2], b[6];
#pragma unroll
            for (int ni = 0; ni < 6; ++ni) {
                int R = wc * 96 + ni * 16 + m;
                b[ni] = *(const bf16x8*)&Bs[R * 64 + (((s * 4 + qd) ^ (R & 7)) * 8)];
            }
#pragma unroll
            for (int mi = 0; mi < 2; ++mi) {
                int R = wr * 32 + mi * 16 + m;
                a[mi] = *(const bf16x8*)&As[R * 64 + (((s * 4 + qd) ^ (R & 7)) * 8)];
            }
            // swapped: D[row=out-dim local qd*4+rr][col=token local m]
#pragma unroll
            for (int mi = 0; mi < 2; ++mi)
#pragma unroll
                for (int ni = 0; ni < 6; ++ni)
                    acc[mi][ni] = __builtin_amdgcn_mfma_f32_16x16x32_bf16(b[ni], a[mi], acc[mi][ni], 0, 0, 0);
        }
        __syncthreads();                 // all MFMA LDS reads done before restage
    }

    // ---- two windows, sequential: epilogue -> barrier -> attention -> barrier ----
    for (int w = 0; w < 2; ++w) {
        if (g == w) {
            // epilogue: Q,K -> QKs[t][0..127]; V -> VT[d][t]
#pragma unroll
            for (int mi = 0; mi < 2; ++mi) {
                int t = (wr & 1) * 32 + mi * 16 + m;       // 0..63 within window
#pragma unroll
                for (int ni = 0; ni < 6; ++ni) {
                    int cn = wc * 96 + ni * 16;
                    float4 bb = *(const float4*)&biash[h * 192 + cn + qd * 4];
                    if (cn < 128) {
                        *(uint2*)&QKs[t * 136 + cn + qd * 4] =
                            pack4(acc[mi][ni][0] + bb.x, acc[mi][ni][1] + bb.y,
                                  acc[mi][ni][2] + bb.z, acc[mi][ni][3] + bb.w);
                    } else {
                        int d0 = cn - 128 + qd * 4;
                        VT[(d0 + 0) * 72 + t] = f2b(acc[mi][ni][0] + bb.x);
                        VT[(d0 + 1) * 72 + t] = f2b(acc[mi][ni][1] + bb.y);
                        VT[(d0 + 2) * 72 + t] = f2b(acc[mi][ni][2] + bb.z);
                        VT[(d0 + 3) * 72 + t] = f2b(acc[mi][ni][3] + bb.w);
                    }
                }
            }
        }
        __syncthreads();                 // QKs/VT(w) visible to group w

        if (g == w) {
            const int q0 = slot * 16;
            f32x4 sa[4];
#pragma unroll
            for (int ni = 0; ni < 4; ++ni) sa[ni] = (f32x4){0.f, 0.f, 0.f, 0.f};
#pragma unroll
            for (int s = 0; s < 2; ++s) {
                bf16x8 qf = *(const bf16x8*)&QKs[(q0 + m) * 136 + s * 32 + qd * 8];
#pragma unroll
                for (int ni = 0; ni < 4; ++ni) {
                    bf16x8 kf = *(const bf16x8*)&QKs[(ni * 16 + m) * 136 + 64 + s * 32 + qd * 8];
                    sa[ni] = __builtin_amdgcn_mfma_f32_16x16x32_bf16(qf, kf, sa[ni], 0, 0, 0);
                }
            }
            const float c1 = 0.125f * 1.4426950408889634f;
#pragma unroll
            for (int rr = 0; rr < 4; ++rr) {
                float mx = -3.4e38f;
#pragma unroll
                for (int ni = 0; ni < 4; ++ni) mx = fmaxf(mx, sa[ni][rr]);
                mx = fmaxf(mx, __shfl_xor(mx, 1, 64));
                mx = fmaxf(mx, __shfl_xor(mx, 2, 64));
                mx = fmaxf(mx, __shfl_xor(mx, 4, 64));
                mx = fmaxf(mx, __shfl_xor(mx, 8, 64));
                float sum = 0.f;
#pragma unroll
                for (int ni = 0; ni < 4; ++ni) {
                    float p = exp2f((sa[ni][rr] - mx) * c1);
                    sa[ni][rr] = p;
                    sum += p;
                }
                sum += __shfl_xor(sum, 1, 64);
                sum += __shfl_xor(sum, 2, 64);
                sum += __shfl_xor(sum, 4, 64);
                sum += __shfl_xor(sum, 8, 64);
                float inv = 1.f / sum;
                int r = qd * 4 + rr;
#pragma unroll
                for (int ni = 0; ni < 4; ++ni)
                    Pw[r * 72 + ni * 16 + m] = f2b(sa[ni][rr] * inv);
            }

            f32x4 oa[4];
#pragma unroll
            for (int ni = 0; ni < 4; ++ni) oa[ni] = (f32x4){0.f, 0.f, 0.f, 0.f};
#pragma unroll
            for (int s = 0; s < 2; ++s) {
                bf16x8 pf = *(const bf16x8*)&Pw[m * 72 + s * 32 + qd * 8];
#pragma unroll
                for (int ni = 0; ni < 4; ++ni) {
                    bf16x8 vf = *(const bf16x8*)&VT[(ni * 16 + m) * 72 + s * 32 + qd * 8];
                    // swapped: D[row=d local][col=q-token local]
                    oa[ni] = __builtin_amdgcn_mfma_f32_16x16x32_bf16(vf, pf, oa[ni], 0, 0, 0);
                }
            }
            u16* dst = ows + (size_t)(rowBase + w * 64 + q0 + m) * 512 + h * 64;
#pragma unroll
            for (int ni = 0; ni < 4; ++ni)
                *(uint2*)&dst[ni * 16 + qd * 4] =
                    pack4(oa[ni][0], oa[ni][1], oa[ni][2], oa[ni][3]);
        }
        __syncthreads();                 // window w's QKs/VT reads done -> region free
    }
}

// ---------------- proj GEMM: M=32768 N=512 K=512, BK=64 ----------------
__global__ __launch_bounds__(256) void proj_gemm(const u16* __restrict__ ows,
        const u16* __restrict__ woT, const float* __restrict__ bo,
        const float* __restrict__ x, float* __restrict__ out) {
    __shared__ u16 S[16384];           // As@0, Bs@8192 (u16); epilogue: Ct fp32 alias
    u16* As = S;
    u16* Bs = S + 8192;
    const int tid = threadIdx.x;
    const int lane = tid & 63, wid = tid >> 6;
    const int wr = wid >> 1, wc = wid & 1;
    const int m = lane & 15, qd = lane >> 4;
    const int rowBase = blockIdx.y * 128;
    const int colBase = blockIdx.x * 128;
    const int c8 = (lane & 7) ^ (lane >> 3);

    f32x4 acc[4][4];
#pragma unroll
    for (int i = 0; i < 4; ++i)
#pragma unroll
        for (int j = 0; j < 4; ++j) acc[i][j] = (f32x4){0.f, 0.f, 0.f, 0.f};

    for (int kt = 0; kt < 8; ++kt) {
        const int k0 = kt * 64;
        __syncthreads();
#pragma unroll
        for (int j = 0; j < 4; ++j) {
            int q = (j * 4 + wid) * 64 + lane;
            int r = (j * 4 + wid) * 8 + (lane >> 3);
            gll16(ows + (size_t)(rowBase + r) * 512 + k0 + c8 * 8, &As[q * 8]);
            gll16(woT + (size_t)(colBase + r) * 512 + k0 + c8 * 8, &Bs[q * 8]);
        }
        __syncthreads();
#pragma unroll
        for (int s = 0; s < 2; ++s) {
            bf16x8 a[4], b[4];
#pragma unroll
            for (int ni = 0; ni < 4; ++ni) {
                int R = wc * 64 + ni * 16 + m;
                b[ni] = *(const bf16x8*)&Bs[R * 64 + (((s * 4 + qd) ^ (R & 7)) * 8)];
            }
#pragma unroll
            for (int mi = 0; mi < 4; ++mi) {
                int R = wr * 64 + mi * 16 + m;
                a[mi] = *(const bf16x8*)&As[R * 64 + (((s * 4 + qd) ^ (R & 7)) * 8)];
            }
            // swapped: D[row=col-dim local][col=token local]
#pragma unroll
            for (int mi = 0; mi < 4; ++mi)
#pragma unroll
                for (int ni = 0; ni < 4; ++ni)
                    acc[mi][ni] = __builtin_amdgcn_mfma_f32_16x16x32_bf16(b[ni], a[mi], acc[mi][ni], 0, 0, 0);
        }
    }
    __syncthreads();                   // staging dead -> Ct may alias

    float* Ct = (float*)S;             // [64 tok][128 col], chunk-XOR swizzled
    for (int p = 0; p < 2; ++p) {
        if (wr == p) {
#pragma unroll
            for (int mi = 0; mi < 4; ++mi) {
                int r = mi * 16 + m;   // token-local within this pass
#pragma unroll
                for (int ni = 0; ni < 4; ++ni) {
                    int ch = (wc * 16 + ni * 4 + qd) ^ (r & 7);
                    *(f32x4*)&Ct[r * 128 + ch * 4] = acc[mi][ni];
                }
            }
        }
        __syncthreads();
        {
            int k = tid >> 2, cseg = tid & 3;      // token-local, 32-col segment
            int row = rowBase + p * 64 + k;        // win*64 + t
            int win = row >> 6, t = row & 63;
            int b_ = win >> 6, wh = (win >> 3) & 7, ww_ = win & 7;
            int ti = t >> 3, tj = t & 7;
            int hh = (wh * 8 + ti + 4) & 63;
            int www = (ww_ * 8 + tj + 4) & 63;
            size_t tok = (size_t)b_ * 4096 + hh * 64 + www;
            const float* xs = &x[tok * 512 + colBase + cseg * 32];
            const float* bs = &bo[colBase + cseg * 32];
            float* os = &out[tok * 512 + colBase + cseg * 32];
#pragma unroll
            for (int j = 0; j < 8; ++j) {
                int ch = (cseg * 8 + j) ^ (k & 7);
                f32x4 c = *(const f32x4*)&Ct[k * 128 + ch * 4];
                float4 xv = *(const float4*)&xs[j * 4];
                float4 bv = *(const float4*)&bs[j * 4];
                float4 o;
                o.x = c[0] + bv.x + xv.x;
                o.y = c[1] + bv.y + xv.y;
                o.z = c[2] + bv.z + xv.z;
                o.w = c[3] + bv.w + xv.w;
                *(float4*)&os[j * 4] = o;
            }
        }
        __syncthreads();
    }
}

extern "C" void kernel_launch(void* const* d_in, const int* in_sizes, int n_in,
                              void* d_out, int out_size, void* d_ws, size_t ws_size,
                              hipStream_t stream) {
    const float* x  = (const float*)d_in[0];
    const float* wq = (const float*)d_in[1];
    const float* bq = (const float*)d_in[2];
    const float* wk = (const float*)d_in[3];
    const float* bk = (const float*)d_in[4];
    const float* wv = (const float*)d_in[5];
    const float* bv = (const float*)d_in[6];
    const float* wo = (const float*)d_in[7];
    const float* bo = (const float*)d_in[8];
    float* out = (float*)d_out;
    char* ws = (char*)d_ws;

    u16*   wqkvh = (u16*)ws;                               // 1536*512*2
    u16*   woT   = (u16*)(ws + 1572864);                   // 512*512*2
    float* biash = (float*)(ws + 1572864 + 524288);        // 1536*4
    size_t off = 2103296;
    u16* xw  = (u16*)(ws + off);                           // 32768*512 u16 = 32 MiB
    u16* ows = xw + (size_t)16777216;                      // 32768*512 u16 = 32 MiB

    const int prepN = 512 * 1536 + 512 * 512 + 1536;
    prep_kernel<<<dim3((prepN + 255) / 256), dim3(256), 0, stream>>>(
        wq, wk, wv, wo, bq, bk, bv, wqkvh, woT, biash);
    pre_kernel<<<dim3(8192), dim3(256), 0, stream>>>(x, xw);
    fused_qkv_attn<<<dim3(2048), dim3(512), 0, stream>>>(xw, wqkvh, biash, ows);
    proj_gemm<<<dim3(4, 256), dim3(256), 0, stream>>>(ows, woT, bo, x, out);
}

// Round 11
// 254.686 us; speedup vs baseline: 1.0572x; 1.0144x over previous
//
#include <hip/hip_runtime.h>

typedef unsigned short u16;
typedef short bf16x8 __attribute__((ext_vector_type(8)));
typedef float f32x4 __attribute__((ext_vector_type(4)));

typedef __attribute__((address_space(3))) unsigned int lds_uint;
typedef __attribute__((address_space(1))) const unsigned int glob_uint;

__device__ __forceinline__ void gll16(const void* g, void* l) {
    __builtin_amdgcn_global_load_lds((glob_uint*)g, (lds_uint*)l, 16, 0, 0);
}

__device__ __forceinline__ u16 f2b(float f) {
    union { float f; unsigned int u; } cv; cv.f = f;
    unsigned int u = cv.u;
    u += 0x7fffu + ((u >> 16) & 1u);
    return (u16)(u >> 16);
}

__device__ __forceinline__ uint2 pack4(float a, float b, float c, float d) {
    uint2 r;
    r.x = (unsigned int)f2b(a) | ((unsigned int)f2b(b) << 16);
    r.y = (unsigned int)f2b(c) | ((unsigned int)f2b(d) << 16);
    return r;
}

// ---------------- merged prep + pre: one launch, fewer kernel boundaries ----------------
// blocks [0, 8192): pre  — x fp32 -> bf16, window-shift permuted (8 elems/thread)
// blocks [8192, 12294): prep — weight reorder + bf16 convert (prepN = 1050112 elems)
__global__ __launch_bounds__(256) void prep_pre_kernel(const float* __restrict__ x,
        const float* __restrict__ wq, const float* __restrict__ wk,
        const float* __restrict__ wv, const float* __restrict__ wo,
        const float* __restrict__ bq, const float* __restrict__ bk,
        const float* __restrict__ bv,
        u16* __restrict__ xw, u16* __restrict__ wqkvh, u16* __restrict__ woT,
        float* __restrict__ biash) {
    if (blockIdx.x < 8192) {
        int idx = blockIdx.x * 256 + threadIdx.x;
        int row = idx >> 6;
        int c = (idx & 63) * 8;
        int b_ = row >> 12, win = (row >> 6) & 63, t = row & 63;
        int wi = win >> 3, wj = win & 7, ti = t >> 3, tj = t & 7;
        int hh = (wi * 8 + ti + 4) & 63, ww = (wj * 8 + tj + 4) & 63;
        const float* src = x + ((size_t)b_ * 4096 + hh * 64 + ww) * 512 + c;
        float4 v0 = *(const float4*)src;
        float4 v1 = *(const float4*)(src + 4);
        ushort4 p0, p1;
        p0.x = f2b(v0.x); p0.y = f2b(v0.y); p0.z = f2b(v0.z); p0.w = f2b(v0.w);
        p1.x = f2b(v1.x); p1.y = f2b(v1.y); p1.z = f2b(v1.z); p1.w = f2b(v1.w);
        u16* dst = xw + (size_t)row * 512 + c;
        *(ushort4*)dst = p0;
        *(ushort4*)(dst + 4) = p1;
    } else {
        int idx = (blockIdx.x - 8192) * 256 + threadIdx.x;
        const int N1 = 512 * 1536;
        const int N2 = 512 * 512;
        if (idx < N1) {
            int k = idx / 1536, n2 = idx % 1536;
            int h = n2 / 192, j = n2 % 192;
            const float* w = (j < 64) ? wq : (j < 128) ? wk : wv;
            wqkvh[(size_t)n2 * 512 + k] = f2b(w[k * 512 + h * 64 + (j & 63)]);
        } else if (idx < N1 + N2) {
            int i = idx - N1;
            int k = i / 512, n = i % 512;
            woT[n * 512 + k] = f2b(wo[k * 512 + n]);
        } else if (idx < N1 + N2 + 1536) {
            int n2 = idx - N1 - N2;
            int h = n2 / 192, j = n2 % 192;
            const float* b = (j < 64) ? bq : (j < 128) ? bk : bv;
            biash[n2] = b[h * 64 + (j & 63)];
        }
    }
}

// ---------------- fused QKV + attention: one block per (window-PAIR, head) ----------------
// R9 structure (M=128, 512 threads / 8 waves, BK=64, 2-barrier loop) + T5 setprio
// around the three MFMA clusters (GEMM / QK^T / PV). Blocks are independent -> co-
// resident blocks sit in different phases (stage vs softmax VALU), so setprio has
// role diversity to arbitrate (m191 regime, not m190's lockstep null).
// LDS (u16): As[0,8192) 128x64; Bs[8192,20480) 192x64.  After GEMM, per-window
// aliases: QKs@0 (64x136=8704), VT@8704 (64x72=4608), Pw@13312+slot*1152.
__global__ __launch_bounds__(512) void fused_qkv_attn(const u16* __restrict__ xw,
        const u16* __restrict__ wqkvh, const float* __restrict__ biash,
        u16* __restrict__ ows) {
    __shared__ u16 S[20480];
    const int tid = threadIdx.x;
    const int lane = tid & 63, wid = tid >> 6;
    const int wr = wid >> 1, wc = wid & 1;      // wr 0..3 (M), wc 0..1 (N)
    const int g = wid >> 2;                     // window group 0/1
    const int slot = wid & 3;                   // attention wave slot
    const int m = lane & 15, qd = lane >> 4;
    const int wp = blockIdx.x & 255;
    const int h = blockIdx.x >> 8;
    const int rowBase = wp * 128;

    u16* As  = S;                     // [128][64]
    u16* Bs  = S + 8192;              // [192][64]
    u16* QKs = S;                     // aliases staging (dead at epilogue)
    u16* VT  = S + 8704;              // aliases Bs
    u16* Pw  = S + 13312 + slot * 1152;   // separate region, no QKs alias

    const u16* Bsrc = wqkvh + (size_t)h * 192 * 512;
    f32x4 acc[2][6];
#pragma unroll
    for (int i = 0; i < 2; ++i)
#pragma unroll
        for (int j = 0; j < 6; ++j) acc[i][j] = (f32x4){0.f, 0.f, 0.f, 0.f};

    for (int kt = 0; kt < 8; ++kt) {
        const int k0 = kt * 64;
#pragma unroll
        for (int j = 0; j < 2; ++j) {          // A: 128x64 = 1024 loads / 512 thr
            int q = j * 512 + tid;
            int r = q >> 3, c = (q & 7) ^ (r & 7);
            gll16(xw + (size_t)(rowBase + r) * 512 + k0 + c * 8, As + q * 8);
        }
#pragma unroll
        for (int j = 0; j < 3; ++j) {          // B: 192x64 = 1536 loads / 512 thr
            int q = j * 512 + tid;
            int r = q >> 3, c = (q & 7) ^ (r & 7);
            gll16(Bsrc + (size_t)r * 512 + k0 + c * 8, Bs + q * 8);
        }
        __syncthreads();                 // staging visible
#pragma unroll
        for (int s = 0; s < 2; ++s) {
            bf16x8 a[2], b[6];
#pragma unroll
            for (int ni = 0; ni < 6; ++ni) {
                int R = wc * 96 + ni * 16 + m;
                b[ni] = *(const bf16x8*)&Bs[R * 64 + (((s * 4 + qd) ^ (R & 7)) * 8)];
            }
#pragma unroll
            for (int mi = 0; mi < 2; ++mi) {
                int R = wr * 32 + mi * 16 + m;
                a[mi] = *(const bf16x8*)&As[R * 64 + (((s * 4 + qd) ^ (R & 7)) * 8)];
            }
            // swapped: D[row=out-dim local qd*4+rr][col=token local m]
            __builtin_amdgcn_s_setprio(1);
#pragma unroll
            for (int mi = 0; mi < 2; ++mi)
#pragma unroll
                for (int ni = 0; ni < 6; ++ni)
                    acc[mi][ni] = __builtin_amdgcn_mfma_f32_16x16x32_bf16(b[ni], a[mi], acc[mi][ni], 0, 0, 0);
            __builtin_amdgcn_s_setprio(0);
        }
        __syncthreads();                 // all MFMA LDS reads done before restage
    }

    // ---- two windows, sequential: epilogue -> barrier -> attention -> barrier ----
    for (int w = 0; w < 2; ++w) {
        if (g == w) {
            // epilogue: Q,K -> QKs[t][0..127]; V -> VT[d][t]
#pragma unroll
            for (int mi = 0; mi < 2; ++mi) {
                int t = (wr & 1) * 32 + mi * 16 + m;       // 0..63 within window
#pragma unroll
                for (int ni = 0; ni < 6; ++ni) {
                    int cn = wc * 96 + ni * 16;
                    float4 bb = *(const float4*)&biash[h * 192 + cn + qd * 4];
                    if (cn < 128) {
                        *(uint2*)&QKs[t * 136 + cn + qd * 4] =
                            pack4(acc[mi][ni][0] + bb.x, acc[mi][ni][1] + bb.y,
                                  acc[mi][ni][2] + bb.z, acc[mi][ni][3] + bb.w);
                    } else {
                        int d0 = cn - 128 + qd * 4;
                        VT[(d0 + 0) * 72 + t] = f2b(acc[mi][ni][0] + bb.x);
                        VT[(d0 + 1) * 72 + t] = f2b(acc[mi][ni][1] + bb.y);
                        VT[(d0 + 2) * 72 + t] = f2b(acc[mi][ni][2] + bb.z);
                        VT[(d0 + 3) * 72 + t] = f2b(acc[mi][ni][3] + bb.w);
                    }
                }
            }
        }
        __syncthreads();                 // QKs/VT(w) visible to group w

        if (g == w) {
            const int q0 = slot * 16;
            f32x4 sa[4];
#pragma unroll
            for (int ni = 0; ni < 4; ++ni) sa[ni] = (f32x4){0.f, 0.f, 0.f, 0.f};
            __builtin_amdgcn_s_setprio(1);
#pragma unroll
            for (int s = 0; s < 2; ++s) {
                bf16x8 qf = *(const bf16x8*)&QKs[(q0 + m) * 136 + s * 32 + qd * 8];
#pragma unroll
                for (int ni = 0; ni < 4; ++ni) {
                    bf16x8 kf = *(const bf16x8*)&QKs[(ni * 16 + m) * 136 + 64 + s * 32 + qd * 8];
                    sa[ni] = __builtin_amdgcn_mfma_f32_16x16x32_bf16(qf, kf, sa[ni], 0, 0, 0);
                }
            }
            __builtin_amdgcn_s_setprio(0);
            const float c1 = 0.125f * 1.4426950408889634f;
#pragma unroll
            for (int rr = 0; rr < 4; ++rr) {
                float mx = -3.4e38f;
#pragma unroll
                for (int ni = 0; ni < 4; ++ni) mx = fmaxf(mx, sa[ni][rr]);
                mx = fmaxf(mx, __shfl_xor(mx, 1, 64));
                mx = fmaxf(mx, __shfl_xor(mx, 2, 64));
                mx = fmaxf(mx, __shfl_xor(mx, 4, 64));
                mx = fmaxf(mx, __shfl_xor(mx, 8, 64));
                float sum = 0.f;
#pragma unroll
                for (int ni = 0; ni < 4; ++ni) {
                    float p = exp2f((sa[ni][rr] - mx) * c1);
                    sa[ni][rr] = p;
                    sum += p;
                }
                sum += __shfl_xor(sum, 1, 64);
                sum += __shfl_xor(sum, 2, 64);
                sum += __shfl_xor(sum, 4, 64);
                sum += __shfl_xor(sum, 8, 64);
                float inv = 1.f / sum;
                int r = qd * 4 + rr;
#pragma unroll
                for (int ni = 0; ni < 4; ++ni)
                    Pw[r * 72 + ni * 16 + m] = f2b(sa[ni][rr] * inv);
            }

            f32x4 oa[4];
#pragma unroll
            for (int ni = 0; ni < 4; ++ni) oa[ni] = (f32x4){0.f, 0.f, 0.f, 0.f};
            __builtin_amdgcn_s_setprio(1);
#pragma unroll
            for (int s = 0; s < 2; ++s) {
                bf16x8 pf = *(const bf16x8*)&Pw[m * 72 + s * 32 + qd * 8];
#pragma unroll
                for (int ni = 0; ni < 4; ++ni) {
                    bf16x8 vf = *(const bf16x8*)&VT[(ni * 16 + m) * 72 + s * 32 + qd * 8];
                    // swapped: D[row=d local][col=q-token local]
                    oa[ni] = __builtin_amdgcn_mfma_f32_16x16x32_bf16(vf, pf, oa[ni], 0, 0, 0);
                }
            }
            __builtin_amdgcn_s_setprio(0);
            u16* dst = ows + (size_t)(rowBase + w * 64 + q0 + m) * 512 + h * 64;
#pragma unroll
            for (int ni = 0; ni < 4; ++ni)
                *(uint2*)&dst[ni * 16 + qd * 4] =
                    pack4(oa[ni][0], oa[ni][1], oa[ni][2], oa[ni][3]);
        }
        __syncthreads();                 // window w's QKs/VT reads done -> region free
    }
}

// ---------------- proj GEMM: M=32768 N=512 K=512, BK=64 ----------------
__global__ __launch_bounds__(256) void proj_gemm(const u16* __restrict__ ows,
        const u16* __restrict__ woT, const float* __restrict__ bo,
        const float* __restrict__ x, float* __restrict__ out) {
    __shared__ u16 S[16384];           // As@0, Bs@8192 (u16); epilogue: Ct fp32 alias
    u16* As = S;
    u16* Bs = S + 8192;
    const int tid = threadIdx.x;
    const int lane = tid & 63, wid = tid >> 6;
    const int wr = wid >> 1, wc = wid & 1;
    const int m = lane & 15, qd = lane >> 4;
    const int rowBase = blockIdx.y * 128;
    const int colBase = blockIdx.x * 128;
    const int c8 = (lane & 7) ^ (lane >> 3);

    f32x4 acc[4][4];
#pragma unroll
    for (int i = 0; i < 4; ++i)
#pragma unroll
        for (int j = 0; j < 4; ++j) acc[i][j] = (f32x4){0.f, 0.f, 0.f, 0.f};

    for (int kt = 0; kt < 8; ++kt) {
        const int k0 = kt * 64;
        __syncthreads();
#pragma unroll
        for (int j = 0; j < 4; ++j) {
            int q = (j * 4 + wid) * 64 + lane;
            int r = (j * 4 + wid) * 8 + (lane >> 3);
            gll16(ows + (size_t)(rowBase + r) * 512 + k0 + c8 * 8, &As[q * 8]);
            gll16(woT + (size_t)(colBase + r) * 512 + k0 + c8 * 8, &Bs[q * 8]);
        }
        __syncthreads();
#pragma unroll
        for (int s = 0; s < 2; ++s) {
            bf16x8 a[4], b[4];
#pragma unroll
            for (int ni = 0; ni < 4; ++ni) {
                int R = wc * 64 + ni * 16 + m;
                b[ni] = *(const bf16x8*)&Bs[R * 64 + (((s * 4 + qd) ^ (R & 7)) * 8)];
            }
#pragma unroll
            for (int mi = 0; mi < 4; ++mi) {
                int R = wr * 64 + mi * 16 + m;
                a[mi] = *(const bf16x8*)&As[R * 64 + (((s * 4 + qd) ^ (R & 7)) * 8)];
            }
            // swapped: D[row=col-dim local][col=token local]
#pragma unroll
            for (int mi = 0; mi < 4; ++mi)
#pragma unroll
                for (int ni = 0; ni < 4; ++ni)
                    acc[mi][ni] = __builtin_amdgcn_mfma_f32_16x16x32_bf16(b[ni], a[mi], acc[mi][ni], 0, 0, 0);
        }
    }
    __syncthreads();                   // staging dead -> Ct may alias

    float* Ct = (float*)S;             // [64 tok][128 col], chunk-XOR swizzled
    for (int p = 0; p < 2; ++p) {
        if (wr == p) {
#pragma unroll
            for (int mi = 0; mi < 4; ++mi) {
                int r = mi * 16 + m;   // token-local within this pass
#pragma unroll
                for (int ni = 0; ni < 4; ++ni) {
                    int ch = (wc * 16 + ni * 4 + qd) ^ (r & 7);
                    *(f32x4*)&Ct[r * 128 + ch * 4] = acc[mi][ni];
                }
            }
        }
        __syncthreads();
        {
            int k = tid >> 2, cseg = tid & 3;      // token-local, 32-col segment
            int row = rowBase + p * 64 + k;        // win*64 + t
            int win = row >> 6, t = row & 63;
            int b_ = win >> 6, wh = (win >> 3) & 7, ww_ = win & 7;
            int ti = t >> 3, tj = t & 7;
            int hh = (wh * 8 + ti + 4) & 63;
            int www = (ww_ * 8 + tj + 4) & 63;
            size_t tok = (size_t)b_ * 4096 + hh * 64 + www;
            const float* xs = &x[tok * 512 + colBase + cseg * 32];
            const float* bs = &bo[colBase + cseg * 32];
            float* os = &out[tok * 512 + colBase + cseg * 32];
#pragma unroll
            for (int j = 0; j < 8; ++j) {
                int ch = (cseg * 8 + j) ^ (k & 7);
                f32x4 c = *(const f32x4*)&Ct[k * 128 + ch * 4];
                float4 xv = *(const float4*)&xs[j * 4];
                float4 bv = *(const float4*)&bs[j * 4];
                float4 o;
                o.x = c[0] + bv.x + xv.x;
                o.y = c[1] + bv.y + xv.y;
                o.z = c[2] + bv.z + xv.z;
                o.w = c[3] + bv.w + xv.w;
                *(float4*)&os[j * 4] = o;
            }
        }
        __syncthreads();
    }
}

extern "C" void kernel_launch(void* const* d_in, const int* in_sizes, int n_in,
                              void* d_out, int out_size, void* d_ws, size_t ws_size,
                              hipStream_t stream) {
    const float* x  = (const float*)d_in[0];
    const float* wq = (const float*)d_in[1];
    const float* bq = (const float*)d_in[2];
    const float* wk = (const float*)d_in[3];
    const float* bk = (const float*)d_in[4];
    const float* wv = (const float*)d_in[5];
    const float* bv = (const float*)d_in[6];
    const float* wo = (const float*)d_in[7];
    const float* bo = (const float*)d_in[8];
    float* out = (float*)d_out;
    char* ws = (char*)d_ws;

    u16*   wqkvh = (u16*)ws;                               // 1536*512*2
    u16*   woT   = (u16*)(ws + 1572864);                   // 512*512*2
    float* biash = (float*)(ws + 1572864 + 524288);        // 1536*4
    size_t off = 2103296;
    u16* xw  = (u16*)(ws + off);                           // 32768*512 u16 = 32 MiB
    u16* ows = xw + (size_t)16777216;                      // 32768*512 u16 = 32 MiB

    const int prepN = 512 * 1536 + 512 * 512 + 1536;       // 1050112
    const int prepBlocks = (prepN + 255) / 256;            // 4102
    prep_pre_kernel<<<dim3(8192 + prepBlocks), dim3(256), 0, stream>>>(
        x, wq, wk, wv, wo, bq, bk, bv, xw, wqkvh, woT, biash);
    fused_qkv_attn<<<dim3(2048), dim3(512), 0, stream>>>(xw, wqkvh, biash, ows);
    proj_gemm<<<dim3(4, 256), dim3(256), 0, stream>>>(ows, woT, bo, x, out);
}